// Round 5
// baseline (6916.002 us; speedup 1.0000x reference)
//
#include <hip/hip_runtime.h>
#include <math.h>

#define BLK 256

typedef _Float16 hf2 __attribute__((ext_vector_type(2)));

// packed f16 atomic add: flat_atomic_pk_add_f16 (gfx90a+/gfx950)
__device__ inline void pk_atomic_add(hf2* p, hf2 v) {
    (void)__builtin_amdgcn_flat_atomic_fadd_v2f16(p, v);
}

// ---------------- fused degree count over 4 edge lists ----------------
__global__ void count_deg4(const int* __restrict__ e0, const int* __restrict__ e1,
                           const int* __restrict__ e2, const int* __restrict__ e3,
                           int* __restrict__ cnt, int E_, int n) {
    int e = blockIdx.x * BLK + threadIdx.x;
    if (e >= E_) return;
    int l = blockIdx.y;
    const int* ei = (l == 0) ? e0 : (l == 1) ? e1 : (l == 2) ? e2 : e3;
    atomicAdd(&cnt[l * n + ei[E_ + e]], 1);
}

__global__ void dinv_from_cnt(const int* __restrict__ cnt, float* __restrict__ dinv, int m) {
    int i = blockIdx.x * BLK + threadIdx.x;
    if (i < m) dinv[i] = rsqrtf((float)cnt[i] + 1.0f);
}

// ---------------- GEMM: hs[node,c] = fp16( (x @ W)[node,c] * dinv[node] ) ----------------
// 64 rows/block, thread owns 4 rows x 1 col. x staged transposed [f][row] (pad 68)
// -> 1 ds_read_b128 (broadcast x4) + 1 broadcast ds_read_b32 per 4 FMAs.
template <int F>
__global__ __launch_bounds__(BLK) void gemm64(const float* __restrict__ x,
                                              const float* __restrict__ W,
                                              const float* __restrict__ dinv,
                                              _Float16* __restrict__ out, int n) {
    constexpr int PAD = 68;
    __shared__ float xs[F * PAD];
    __shared__ float Ws[F * 16];
    int tid = threadIdx.x;
    for (int i = tid; i < F * 16; i += BLK) Ws[i] = W[i];
    int row0 = blockIdx.x * 64;
    for (int i = tid; i < 64 * F; i += BLK) {
        int r = i / F, f = i - r * F;
        int gr = row0 + r;
        xs[f * PAD + r] = (gr < n) ? x[(long long)gr * F + f] : 0.0f;
    }
    __syncthreads();
    int c = tid & 15;
    int r4 = (tid >> 4) << 2;  // 0,4,...,60
    float a0 = 0.f, a1 = 0.f, a2 = 0.f, a3 = 0.f;
    for (int f = 0; f < F; ++f) {
        float w = Ws[f * 16 + c];
        const float4 a = *(const float4*)&xs[f * PAD + r4];
        a0 += a.x * w; a1 += a.y * w; a2 += a.z * w; a3 += a.w * w;
    }
    float r[4] = {a0, a1, a2, a3};
#pragma unroll
    for (int j = 0; j < 4; ++j) {
        int gr = row0 + r4 + j;
        if (gr < n) out[gr * 16 + c] = (_Float16)(r[j] * dinv[gr]);
    }
}

// ---------------- edge scatter: acc[dst] += hs[src], 8 pk-f16 atomics/edge ----------------
__global__ void edge_agg16(const int* __restrict__ ei, const _Float16* __restrict__ hs,
                           _Float16* __restrict__ acc, int E_) {
    int e = blockIdx.x * BLK + threadIdx.x;
    if (e >= E_) return;
    int s = ei[e];
    int d = ei[E_ + e];
    const hf2* src = (const hf2*)(hs + (size_t)s * 16);
    hf2* dst = (hf2*)(acc + (size_t)d * 16);
    hf2 v[8];
#pragma unroll
    for (int j = 0; j < 8; ++j) v[j] = src[j];
#pragma unroll
    for (int j = 0; j < 8; ++j) pk_atomic_add(dst + j, v[j]);
}

// ---------------- edge scatter H=10: 5 pk-f16 atomics/edge ----------------
__global__ void edge_agg10(const int* __restrict__ ei, const _Float16* __restrict__ hs,
                           _Float16* __restrict__ acc, int E_) {
    int e = blockIdx.x * BLK + threadIdx.x;
    if (e >= E_) return;
    int s = ei[e];
    int d = ei[E_ + e];
    const hf2* src = (const hf2*)(hs + (size_t)s * 10);
    hf2* dst = (hf2*)(acc + (size_t)d * 10);
    hf2 v[5];
#pragma unroll
    for (int j = 0; j < 5; ++j) v[j] = src[j];
#pragma unroll
    for (int j = 0; j < 5; ++j) pk_atomic_add(dst + j, v[j]);
}

// ---------------- finalize: out = bias + dinv*(hs + acc) + skips ----------------
__global__ void finalize16(const _Float16* __restrict__ hs, const _Float16* __restrict__ acc,
                           const float* __restrict__ dinv, const float* __restrict__ bias,
                           const float* __restrict__ add1, const float* __restrict__ add2,
                           float* __restrict__ out, int n) {
    int t = blockIdx.x * BLK + threadIdx.x;
    int node = t >> 4, k = t & 15;
    if (node >= n) return;
    float dv = dinv[node];
    float v = bias[k] + dv * ((float)hs[t] + (float)acc[t]);
    if (add1) { float a = add1[t]; v += fmaxf(a, 0.0f) + a; }
    if (add2) v += add2[t];
    out[t] = v;
}

// ---------------- final GEMM: p10 = fp16( (relu(hf) @ We) * dinv ), stride 10 ----------------
__global__ void gemm_final(const float* __restrict__ hf, const float* __restrict__ We,
                           const float* __restrict__ dinv, _Float16* __restrict__ out, int n) {
    __shared__ float Ws[160];
    if (threadIdx.x < 160) Ws[threadIdx.x] = We[threadIdx.x];
    __syncthreads();
    int t = blockIdx.x * BLK + threadIdx.x;
    if (t >= n * 10) return;
    int i = t / 10, j = t - i * 10;
    float a = 0.0f;
#pragma unroll
    for (int k = 0; k < 16; ++k) a += fmaxf(hf[i * 16 + k], 0.0f) * Ws[k * 10 + j];
    out[t] = (_Float16)(a * dinv[i]);
}

// ---------------- finalize + log_softmax, thread per node ----------------
__global__ void final_ls(const _Float16* __restrict__ p10, const _Float16* __restrict__ acc10,
                         const float* __restrict__ dinv, const float* __restrict__ be,
                         float* __restrict__ out, int n) {
    int i = blockIdx.x * BLK + threadIdx.x;
    if (i >= n) return;
    float dv = dinv[i];
    float v[10];
    float m = -INFINITY;
#pragma unroll
    for (int j = 0; j < 10; ++j) {
        v[j] = be[j] + dv * ((float)p10[i * 10 + j] + (float)acc10[i * 10 + j]);
        m = fmaxf(m, v[j]);
    }
    float s = 0.0f;
#pragma unroll
    for (int j = 0; j < 10; ++j) s += expf(v[j] - m);
    float ls = logf(s) + m;
#pragma unroll
    for (int j = 0; j < 10; ++j) out[i * 10 + j] = v[j] - ls;
}

extern "C" void kernel_launch(void* const* d_in, const int* in_sizes, int n_in,
                              void* d_out, int out_size, void* d_ws, size_t ws_size,
                              hipStream_t stream) {
    const float* x_parent = (const float*)d_in[0];
    const float* x_child1 = (const float*)d_in[1];
    const float* x_child2 = (const float*)d_in[2];
    const float* x_fd     = (const float*)d_in[3];
    const int* e_p  = (const int*)d_in[4];
    const int* e_c1 = (const int*)d_in[5];
    const int* e_c2 = (const int*)d_in[6];
    const int* e_fd = (const int*)d_in[7];
    const float* W1 = (const float*)d_in[8];
    const float* b1 = (const float*)d_in[9];
    const float* W2 = (const float*)d_in[10];
    const float* b2 = (const float*)d_in[11];
    const float* W3 = (const float*)d_in[12];
    const float* b3 = (const float*)d_in[13];
    const float* We = (const float*)d_in[14];
    const float* be = (const float*)d_in[15];

    const int n  = in_sizes[0] / 128;   // 100000
    const int E_ = in_sizes[4] / 2;     // 3200000

    float* ws = (float*)d_ws;
    float* dinv = ws;                                  // 4n f32
    float* hA   = ws + (size_t)4 * n;                  // 16n f32 (hp, later hf)
    float* hc1  = hA  + (size_t)16 * n;                // 16n f32
    float* hc2  = hc1 + (size_t)16 * n;                // 16n f32
    _Float16* hs  = (_Float16*)(hc2 + (size_t)16 * n); // 16n f16 (also p10)
    _Float16* acc = hs + (size_t)16 * n;               // 16n f16 (also acc10)
    int* cnt    = (int*)(acc + (size_t)16 * n);        // 4n int

    float* dinv_p  = dinv;
    float* dinv_c1 = dinv + (size_t)n;
    float* dinv_c2 = dinv + (size_t)2 * n;
    float* dinv_fd = dinv + (size_t)3 * n;

    const int gN   = (n + BLK - 1) / BLK;
    const int gN16 = (n * 16 + BLK - 1) / BLK;
    const int gN10 = (n * 10 + BLK - 1) / BLK;
    const int gE   = (E_ + BLK - 1) / BLK;
    const int g4N  = (4 * n + BLK - 1) / BLK;
    const int gR64 = (n + 63) / 64;

    // degrees for all 4 edge lists in one pass
    (void)hipMemsetAsync(cnt, 0, (size_t)4 * n * sizeof(int), stream);
    count_deg4<<<dim3(gE, 4), BLK, 0, stream>>>(e_p, e_c1, e_c2, e_fd, cnt, E_, n);
    dinv_from_cnt<<<g4N, BLK, 0, stream>>>(cnt, dinv, 4 * n);

    // L1: hp = conv(x_parent, e_p, W1, b1)
    gemm64<128><<<gR64, BLK, 0, stream>>>(x_parent, W1, dinv_p, hs, n);
    (void)hipMemsetAsync(acc, 0, (size_t)16 * n * sizeof(_Float16), stream);
    edge_agg16<<<gE, BLK, 0, stream>>>(e_p, hs, acc, E_);
    finalize16<<<gN16, BLK, 0, stream>>>(hs, acc, dinv_p, b1, nullptr, nullptr, hA, n);

    // L2: hc1 = conv(x_child1, e_c1, W2, b2) + relu(hp) + hp
    gemm64<129><<<gR64, BLK, 0, stream>>>(x_child1, W2, dinv_c1, hs, n);
    (void)hipMemsetAsync(acc, 0, (size_t)16 * n * sizeof(_Float16), stream);
    edge_agg16<<<gE, BLK, 0, stream>>>(e_c1, hs, acc, E_);
    finalize16<<<gN16, BLK, 0, stream>>>(hs, acc, dinv_c1, b2, hA, nullptr, hc1, n);

    // L3: hc2 = conv(x_child2, e_c2, W3, b3) + relu(hc1) + hc1
    gemm64<130><<<gR64, BLK, 0, stream>>>(x_child2, W3, dinv_c2, hs, n);
    (void)hipMemsetAsync(acc, 0, (size_t)16 * n * sizeof(_Float16), stream);
    edge_agg16<<<gE, BLK, 0, stream>>>(e_c2, hs, acc, E_);
    finalize16<<<gN16, BLK, 0, stream>>>(hs, acc, dinv_c2, b3, hc1, nullptr, hc2, n);

    // L4: hf = conv(x_fd, e_fd, W2, b2) + relu(hc2) + hc1 + hc2   (hf -> hA)
    gemm64<129><<<gR64, BLK, 0, stream>>>(x_fd, W2, dinv_fd, hs, n);
    (void)hipMemsetAsync(acc, 0, (size_t)16 * n * sizeof(_Float16), stream);
    edge_agg16<<<gE, BLK, 0, stream>>>(e_fd, hs, acc, E_);
    finalize16<<<gN16, BLK, 0, stream>>>(hs, acc, dinv_fd, b2, hc2, hc1, hA, n);

    // L5: out = log_softmax(conv(relu(hf), e_fd, We, be))
    gemm_final<<<gN10, BLK, 0, stream>>>(hA, We, dinv_fd, hs, n);        // hs = p10
    (void)hipMemsetAsync(acc, 0, (size_t)10 * n * sizeof(_Float16), stream);
    edge_agg10<<<gE, BLK, 0, stream>>>(e_fd, hs, acc, E_);
    final_ls<<<gN, BLK, 0, stream>>>(hs, acc, dinv_fd, be, (float*)d_out, n);
}